// Round 8
// baseline (525.671 us; speedup 1.0000x reference)
//
#include <hip/hip_runtime.h>
#include <math.h>

#define DD 128

typedef __attribute__((ext_vector_type(8))) short short8;   // 8 x bf16 bits
typedef __attribute__((ext_vector_type(4))) float f32x4;
typedef __attribute__((ext_vector_type(4))) _Float16 f16x4;
typedef __attribute__((ext_vector_type(8))) _Float16 f16x8;

__device__ inline short bf16hi(float x) {
  unsigned u = __float_as_uint(x);
  unsigned r = u + 0x7fffu + ((u >> 16) & 1u);  // RTNE
  return (short)(r >> 16);
}
__device__ inline float bf16tof(short h) {
  return __uint_as_float(((unsigned)(unsigned short)h) << 16);
}
__device__ inline void split2(float x, short& hi, short& lo) {  // RTNE
  hi = bf16hi(x);
  float rem = x - bf16tof(hi);
  lo = bf16hi(rem);
}
__device__ inline void splitT(float x, short& hi, short& lo) {  // truncation (cheap)
  unsigned u = __float_as_uint(x);
  hi = (short)(u >> 16);
  float rem = x - __uint_as_float(u & 0xffff0000u);
  lo = (short)(__float_as_uint(rem) >> 16);
}

// async global->LDS, 16B per lane; LDS dest is wave-uniform base + lane*16.
__device__ inline void gload_lds16(const void* g, void* l) {
  __builtin_amdgcn_global_load_lds((const __attribute__((address_space(1))) unsigned*)g,
                                   (__attribute__((address_space(3))) unsigned*)l, 16, 0, 0);
}

// ---------------- small helper kernels ----------------
__global__ __launch_bounds__(128) void zero128_kernel(float* p) { p[threadIdx.x] = 0.f; }

__global__ __launch_bounds__(256) void colsum_kernel(const float* __restrict__ x,
                                                     float* __restrict__ colsum, int N) {
  int col = threadIdx.x & 127;
  int part = (blockIdx.x * blockDim.x + threadIdx.x) >> 7;
  int nparts = (gridDim.x * blockDim.x) >> 7;
  float s = 0.f;
  for (int r = part; r < N; r += nparts) s += x[(size_t)r * DD + col];
  atomicAdd(&colsum[col], s);
}

__global__ __launch_bounds__(128) void glb_kernel(const float* __restrict__ colsum,
                                                  const float* __restrict__ glb_W,
                                                  const float* __restrict__ glb_b,
                                                  float* __restrict__ g, float invN) {
  __shared__ float m[DD];
  int j = threadIdx.x;
  m[j] = colsum[j] * invN;
  __syncthreads();
  float s = glb_b[j];
#pragma unroll 8
  for (int k = 0; k < DD; ++k) s = fmaf(m[k], glb_W[k * DD + j], s);
  g[j] = fmaxf(s, 0.f);
}

// W2U = msg_W2 @ upd_W1[128:256] (128x128), v2 = msg_b2 @ upd_W1[128:256] (128)
__global__ __launch_bounds__(256) void wprep_kernel(const float* __restrict__ msg_W2,
                                                    const float* __restrict__ msg_b2,
                                                    const float* __restrict__ upd_W1,
                                                    float* __restrict__ W2U,
                                                    float* __restrict__ v2) {
  int o = blockIdx.x * 256 + threadIdx.x;
  if (o < 16384) {
    int r = o >> 7, c = o & 127;
    float s = 0.f;
#pragma unroll 8
    for (int j = 0; j < 128; ++j) s = fmaf(msg_W2[r * 128 + j], upd_W1[(128 + j) * 128 + c], s);
    W2U[o] = s;
  } else if (o < 16512) {
    int c = o - 16384;
    float s = 0.f;
#pragma unroll 8
    for (int j = 0; j < 128; ++j) s = fmaf(msg_b2[j], upd_W1[(128 + j) * 128 + c], s);
    v2[c] = s;
  }
}

// ---------------- CSR build: histogram -> parallel scan -> scatter ----------------
__global__ __launch_bounds__(256) void hist_kernel(const int* __restrict__ dst,
                                                   int* __restrict__ rowptr, int E) {
  for (int e = blockIdx.x * blockDim.x + threadIdx.x; e < E; e += gridDim.x * blockDim.x)
    atomicAdd(&rowptr[dst[e] + 1], 1);
}

__global__ __launch_bounds__(1024) void scan1_kernel(int* __restrict__ a,
                                                     int* __restrict__ bsum, int n) {
  __shared__ int buf[1024];
  const int tid = threadIdx.x;
  int i = blockIdx.x * 1024 + tid;
  buf[tid] = (i < n) ? a[i] : 0;
  __syncthreads();
#pragma unroll
  for (int off = 1; off < 1024; off <<= 1) {
    int t = (tid >= off) ? buf[tid - off] : 0;
    __syncthreads();
    buf[tid] += t;
    __syncthreads();
  }
  if (i < n) a[i] = buf[tid];
  if (tid == 1023) bsum[blockIdx.x] = buf[1023];
}

__global__ __launch_bounds__(1024) void scan2_kernel(int* __restrict__ a, int n) {
  __shared__ int buf[1024];
  const int tid = threadIdx.x;
  buf[tid] = (tid < n) ? a[tid] : 0;
  __syncthreads();
#pragma unroll
  for (int off = 1; off < 1024; off <<= 1) {
    int t = (tid >= off) ? buf[tid - off] : 0;
    __syncthreads();
    buf[tid] += t;
    __syncthreads();
  }
  if (tid < n) a[tid] = buf[tid];
}

__global__ __launch_bounds__(1024) void scan3_kernel(int* __restrict__ a,
                                                     const int* __restrict__ bsum, int n) {
  int b = blockIdx.x + 1;
  int i = b * 1024 + threadIdx.x;
  if (i < n) a[i] += bsum[b - 1];
}

__global__ __launch_bounds__(256) void scatter_kernel(const int* __restrict__ src,
                                                      const int* __restrict__ dst,
                                                      int* __restrict__ cursor,
                                                      int* __restrict__ sortedSrc, int E) {
  for (int e = blockIdx.x * blockDim.x + threadIdx.x; e < E; e += gridDim.x * blockDim.x) {
    int pos = atomicAdd(&cursor[dst[e]], 1);
    sortedSrc[pos] = src[e];
  }
}

// ---------------- weight prep: ALL matrices to MFMA-fragment-major hi/lo ----------
__global__ __launch_bounds__(256) void conv_kernel(
    const float* __restrict__ msg_W1, const float* __restrict__ att_W1,
    const float* __restrict__ upd_W1, const float* __restrict__ upd_W2,
    const float* __restrict__ W2U,
    short* __restrict__ WbigF, short* __restrict__ U1F, short* __restrict__ U2F) {
  int i = blockIdx.x * 256 + threadIdx.x;  // 0 .. 28671
  if (i < 16384) {
    int lane = i & 63, p = (i >> 6) & 1, n = (i >> 7) & 31, c = i >> 12;
    int col = n * 16 + (lane & 15);
#pragma unroll
    for (int j = 0; j < 8; ++j) {
      int k = c * 32 + ((lane >> 4) & 3) * 8 + j;
      float v;
      if (col < 128)      v = msg_W1[k * 128 + col];
      else if (col < 256) v = att_W1[k * 128 + (col - 128)];
      else if (col < 384) v = msg_W1[(k + 128) * 128 + (col - 256)];
      else                v = att_W1[(k + 128) * 128 + (col - 384)];
      short hi, lo; splitT(v, hi, lo);
      WbigF[(size_t)i * 8 + j] = p ? lo : hi;
    }
  } else if (i < 24576) {
    int u = i - 16384;  // t(3b) n(3b) p(1b) lane(6b)
    int lane = u & 63, p = (u >> 6) & 1, n = (u >> 7) & 7, t = u >> 10;
    int col = n * 16 + (lane & 15);
#pragma unroll
    for (int j = 0; j < 8; ++j) {
      int k = t * 32 + (lane >> 4) * 8 + j;
      float v = (k < 128) ? upd_W1[k * 128 + col] : W2U[(k - 128) * 128 + col];
      short hi, lo; split2(v, hi, lo);
      U1F[(size_t)u * 8 + j] = p ? lo : hi;
    }
  } else {
    int u = i - 24576;  // t(2b) n(3b) p(1b) lane(6b)
    int lane = u & 63, p = (u >> 6) & 1, n = (u >> 7) & 7, t = u >> 10;
    int col = n * 16 + (lane & 15);
#pragma unroll
    for (int j = 0; j < 8; ++j) {
      int k = t * 32 + (lane >> 4) * 8 + j;
      float v = upd_W2[k * 128 + col];
      short hi, lo; split2(v, hi, lo);
      U2F[(size_t)u * 8 + j] = p ? lo : hi;
    }
  }
}

// ---------------- Z-prep GEMM (step 0 only): ----------------
// Zsrc[N x 256] fp16 = h @ Wbig[:,0:256] + [msg_b1|att_b1]
// Zdst[N x 256] fp32 = h @ Wbig[:,256:512]
__global__ __launch_bounds__(256, 2) void zprep_kernel(
    const float* __restrict__ h, const short* __restrict__ WbigF,
    const float* __restrict__ msg_b1, const float* __restrict__ att_b1,
    _Float16* __restrict__ Zsrc, float* __restrict__ Zdst, int N) {
  const int tid = threadIdx.x;
  const int w = tid >> 6;
  const int lane = tid & 63;
  const int m16 = lane & 15, q = lane >> 4;
  const int r0 = blockIdx.x * 32;

  f32x4 acc[2][8];
#pragma unroll
  for (int nt = 0; nt < 8; ++nt) {
    int col = w * 128 + nt * 16 + m16;
    float b = (col < 128) ? msg_b1[col] : ((col < 256) ? att_b1[col - 128] : 0.f);
    acc[0][nt] = (f32x4){b, b, b, b};
    acc[1][nt] = (f32x4){b, b, b, b};
  }

  for (int c = 0; c < 4; ++c) {
    short8 ah[2], al[2];
#pragma unroll
    for (int mt = 0; mt < 2; ++mt) {
      int row = min(r0 + mt * 16 + m16, N - 1);
      const float* p = h + (size_t)row * DD + c * 32 + q * 8;
      float4 v0 = *(const float4*)p;
      float4 v1 = *(const float4*)(p + 4);
      float f[8] = {v0.x, v0.y, v0.z, v0.w, v1.x, v1.y, v1.z, v1.w};
#pragma unroll
      for (int j = 0; j < 8; ++j) { short hi, lo; splitT(f[j], hi, lo); ah[mt][j] = hi; al[mt][j] = lo; }
    }
#pragma unroll
    for (int nt = 0; nt < 8; ++nt) {
      int ng = w * 8 + nt;
      const short* bp = WbigF + ((size_t)((c * 32 + ng) * 2) * 64 + lane) * 8;
      short8 bh = *(const short8*)bp;
      short8 bl = *(const short8*)(bp + 512);
#pragma unroll
      for (int mt = 0; mt < 2; ++mt) {
        acc[mt][nt] = __builtin_amdgcn_mfma_f32_16x16x32_bf16(ah[mt], bh, acc[mt][nt], 0, 0, 0);
        acc[mt][nt] = __builtin_amdgcn_mfma_f32_16x16x32_bf16(al[mt], bh, acc[mt][nt], 0, 0, 0);
        acc[mt][nt] = __builtin_amdgcn_mfma_f32_16x16x32_bf16(ah[mt], bl, acc[mt][nt], 0, 0, 0);
      }
    }
  }

#pragma unroll
  for (int mt = 0; mt < 2; ++mt)
#pragma unroll
    for (int r = 0; r < 4; ++r) {
      int row = r0 + mt * 16 + q * 4 + r;
      if (row < N) {
#pragma unroll
        for (int nt = 0; nt < 8; ++nt) {
          int col = w * 128 + nt * 16 + m16;
          float v = acc[mt][nt][r];
          if (col < 256) Zsrc[(size_t)row * 256 + col] = (_Float16)v;
          else           Zdst[(size_t)row * 256 + (col - 256)] = v;
        }
      }
    }
}

// ---------------- CSR aggregation: lane-split single-16B gather per edge ----------
// 32 lanes per node: lanes 0-15 own 8 message channels each, lanes 16-31 own 8
// attention channels each -> ONE f16x8 load per lane per edge (was two 8B loads).
// shfl_xor tree sums the a-lanes' partial dot-products to all 32 lanes.
__global__ __launch_bounds__(256) void aggcsr_kernel(
    const _Float16* __restrict__ Zsrc, const float* __restrict__ Zdst,
    const int* __restrict__ rowptr, const int* __restrict__ sortedSrc,
    const float* __restrict__ att_W2, const float* __restrict__ att_b2,
    float* __restrict__ aggH, float* __restrict__ aggA, int N) {
  const int node = blockIdx.x * 8 + (threadIdx.x >> 5);
  const int c = threadIdx.x & 31;
  if (node >= N) return;

  const int isA = c >> 4;            // 0 = message half, 1 = attention half
  const int ch = (c & 15) * 8;       // channel base within the half
  const int off = isA * 128 + ch;    // f16 offset within a Zsrc row

  float w[8], d[8];
  {
    const float4 w0 = *(const float4*)(att_W2 + ch);
    const float4 w1 = *(const float4*)(att_W2 + ch + 4);
    w[0] = w0.x; w[1] = w0.y; w[2] = w0.z; w[3] = w0.w;
    w[4] = w1.x; w[5] = w1.y; w[6] = w1.z; w[7] = w1.w;
    const float* Zn = Zdst + (size_t)node * 256 + off;
    const float4 d0 = *(const float4*)Zn;
    const float4 d1 = *(const float4*)(Zn + 4);
    d[0] = d0.x; d[1] = d0.y; d[2] = d0.z; d[3] = d0.w;
    d[4] = d1.x; d[5] = d1.y; d[6] = d1.z; d[7] = d1.w;
  }
  const float ab2 = att_b2[0];

  float a[8] = {0.f, 0.f, 0.f, 0.f, 0.f, 0.f, 0.f, 0.f};
  float aA = 0.f;
  const int b = rowptr[node], e = rowptr[node + 1];

  int i = b;
  int nx0 = (b < e) ? sortedSrc[b] : 0;
  int nx1 = (b + 1 < e) ? sortedSrc[b + 1] : 0;
  for (; i + 1 < e; i += 2) {
    const int s0 = nx0, s1 = nx1;
    if (i + 2 < e) nx0 = sortedSrc[i + 2];     // prefetch next pair's indices
    if (i + 3 < e) nx1 = sortedSrc[i + 3];
    f16x8 z0 = *(const f16x8*)(Zsrc + (size_t)s0 * 256 + off);
    f16x8 z1 = *(const f16x8*)(Zsrc + (size_t)s1 * 256 + off);

    float v0[8], v1[8];
#pragma unroll
    for (int j = 0; j < 8; ++j) {
      v0[j] = fmaxf((float)z0[j] + d[j], 0.f);
      v1[j] = fmaxf((float)z1[j] + d[j], 0.f);
    }
    float p0 = 0.f, p1 = 0.f;
    if (isA) {
#pragma unroll
      for (int j = 0; j < 8; ++j) {
        p0 = fmaf(v0[j], w[j], p0);
        p1 = fmaf(v1[j], w[j], p1);
      }
    }
#pragma unroll
    for (int o = 1; o < 32; o <<= 1) {
      p0 += __shfl_xor(p0, o);
      p1 += __shfl_xor(p1, o);
    }
    float t0 = 1.f / (1.f + expf(-(p0 + ab2)));
    float t1 = 1.f / (1.f + expf(-(p1 + ab2)));
    aA += t0 + t1;
#pragma unroll
    for (int j = 0; j < 8; ++j) a[j] = fmaf(t0, v0[j], fmaf(t1, v1[j], a[j]));
  }
  if (i < e) {
    const int s0 = nx0;
    f16x8 z0 = *(const f16x8*)(Zsrc + (size_t)s0 * 256 + off);
    float v0[8];
#pragma unroll
    for (int j = 0; j < 8; ++j) v0[j] = fmaxf((float)z0[j] + d[j], 0.f);
    float p0 = 0.f;
    if (isA) {
#pragma unroll
      for (int j = 0; j < 8; ++j) p0 = fmaf(v0[j], w[j], p0);
    }
#pragma unroll
    for (int o = 1; o < 32; o <<= 1) p0 += __shfl_xor(p0, o);
    float t0 = 1.f / (1.f + expf(-(p0 + ab2)));
    aA += t0;
#pragma unroll
    for (int j = 0; j < 8; ++j) a[j] = fmaf(t0, v0[j], a[j]);
  }

  if (!isA) {
    *(float4*)(aggH + (size_t)node * DD + ch) = (float4){a[0], a[1], a[2], a[3]};
    *(float4*)(aggH + (size_t)node * DD + ch + 4) = (float4){a[4], a[5], a[6], a[7]};
  }
  if (c == 0) aggA[node] = aA;
}

// ---------------- node update: LDS-staged weights via 2-phase gload_lds ring ----
// (R4 form verbatim — measured 102 us; known best for this structure.)
template <int DOZ>
__global__ __launch_bounds__(256, 3) void node_mfma_kernel(
    const float* __restrict__ h, const float* __restrict__ aggH,
    const float* __restrict__ aggA, const float* __restrict__ v2,
    const short* __restrict__ U1F, const short* __restrict__ U2F,
    const float* __restrict__ upd_b1, const float* __restrict__ upd_b2,
    const float* __restrict__ g, float* __restrict__ out, int N,
    const short* __restrict__ WbigF, const float* __restrict__ msg_b1,
    const float* __restrict__ att_b1, _Float16* __restrict__ Zsrc,
    float* __restrict__ Zdst) {
  // 51200 B total -> 3 blocks/CU.
  __shared__ __align__(16) short smem[25600];
  short* WBUF = smem;             // 2 x 4096 shorts (2 x 8KB ring)
  short* HIDhi = smem + 8192;     // 64 x 136
  short* HIDlo = smem + 16896;    // 64 x 136

  const int tid = threadIdx.x;
  const int wave = tid >> 6;
  const int lane = tid & 63;
  const int m16 = lane & 15;
  const int q = lane >> 4;

  const int n0 = blockIdx.x * 64;
  const int nA = n0 + wave * 16 + m16;
  const int nAc = min(nA, N - 1);
  const float* rs = h + (size_t)nAc * DD;
  const float* rd = aggH + (size_t)nAc * DD;

#define STAGE(i)                                                                   \
  {                                                                                \
    const char* src_ = (const char*)(((i) < 16) ? U1F : U2F) +                     \
                       ((((i) < 16) ? ((i) >> 1) : (((i)-16) >> 1)) * 16384) +     \
                       (((i)&1) * 8192);                                           \
    char* dst_ = (char*)(WBUF + ((i)&1) * 4096);                                   \
    _Pragma("unroll") for (int r_ = 0; r_ < 2; ++r_) {                             \
      gload_lds16(src_ + r_ * 4096 + tid * 16, dst_ + r_ * 4096 + wave * 1024);    \
    }                                                                              \
  }

  // A-fragments for GEMM1 (all 8 t upfront, hi/lo RTNE split)
  short8 a1h[8], a1l[8];
#pragma unroll
  for (int t = 0; t < 8; ++t) {
    const float* base = ((t < 4) ? (rs + t * 32) : (rd + (t - 4) * 32)) + q * 8;
    float4 v0 = *(const float4*)(base);
    float4 v1 = *(const float4*)(base + 4);
    float f[8] = {v0.x, v0.y, v0.z, v0.w, v1.x, v1.y, v1.z, v1.w};
#pragma unroll
    for (int j = 0; j < 8; ++j) { short hi, lo; split2(f[j], hi, lo); a1h[t][j] = hi; a1l[t][j] = lo; }
  }

  f32x4 acc[8];
#pragma unroll
  for (int n = 0; n < 8; ++n) {
    float b = upd_b1[n * 16 + m16];
    acc[n] = (f32x4){b, b, b, b};
  }

  STAGE(0);
  __syncthreads();

  // ---- GEMM1: halves 0..15 ----
#pragma unroll
  for (int i = 0; i < 16; ++i) {
    STAGE(i + 1);  // i==15 stages the first U2F half
    const short* bb = WBUF + (i & 1) * 4096;
    const int t = i >> 1;
#pragma unroll
    for (int n = 0; n < 4; ++n) {
      const short* bp = bb + n * 1024 + lane * 8;
      short8 bh = *(const short8*)bp;
      short8 bl = *(const short8*)(bp + 512);
      const int ng = (i & 1) * 4 + n;
      acc[ng] = __builtin_amdgcn_mfma_f32_16x16x32_bf16(a1h[t], bh, acc[ng], 0, 0, 0);
      acc[ng] = __builtin_amdgcn_mfma_f32_16x16x32_bf16(a1l[t], bh, acc[ng], 0, 0, 0);
      acc[ng] = __builtin_amdgcn_mfma_f32_16x16x32_bf16(a1h[t], bl, acc[ng], 0, 0, 0);
    }
    __syncthreads();
  }

  // fold in aggA (x) v2
  {
    float aAv[4];
#pragma unroll
    for (int r = 0; r < 4; ++r) aAv[r] = aggA[min(n0 + wave * 16 + q * 4 + r, N - 1)];
#pragma unroll
    for (int n = 0; n < 8; ++n) {
      float vv = v2[n * 16 + m16];
#pragma unroll
      for (int r = 0; r < 4; ++r) acc[n][r] = fmaf(aAv[r], vv, acc[n][r]);
    }
  }

  // ReLU + hi/lo split into LDS; SAME-WAVE rows -> no barrier needed.
#pragma unroll
  for (int n = 0; n < 8; ++n) {
    int col = n * 16 + m16;
#pragma unroll
    for (int r = 0; r < 4; ++r) {
      int row = wave * 16 + q * 4 + r;
      float v = fmaxf(acc[n][r], 0.f);
      short hi, lo; split2(v, hi, lo);
      HIDhi[row * 136 + col] = hi;
      HIDlo[row * 136 + col] = lo;
    }
  }

  short8 a2h[4], a2l[4];
  {
    int mrow = wave * 16 + m16;
#pragma unroll
    for (int t = 0; t < 4; ++t) {
      a2h[t] = *(const short8*)(HIDhi + mrow * 136 + t * 32 + q * 8);
      a2l[t] = *(const short8*)(HIDlo + mrow * 136 + t * 32 + q * 8);
    }
  }

  f32x4 acc2[8];
#pragma unroll
  for (int n = 0; n < 8; ++n) {
    float b = upd_b2[n * 16 + m16];
    acc2[n] = (f32x4){b, b, b, b};
  }

  // ---- GEMM2: halves 16..23 (half 16 staged during GEMM1's tail) ----
#pragma unroll
  for (int i = 16; i < 24; ++i) {
    if (i < 23) STAGE(i + 1);
    const short* bb = WBUF + (i & 1) * 4096;
    const int t = (i - 16) >> 1;
#pragma unroll
    for (int n = 0; n < 4; ++n) {
      const short* bp = bb + n * 1024 + lane * 8;
      short8 bh = *(const short8*)bp;
      short8 bl = *(const short8*)(bp + 512);
      const int ng = (i & 1) * 4 + n;
      acc2[ng] = __builtin_amdgcn_mfma_f32_16x16x32_bf16(a2h[t], bh, acc2[ng], 0, 0, 0);
      acc2[ng] = __builtin_amdgcn_mfma_f32_16x16x32_bf16(a2l[t], bh, acc2[ng], 0, 0, 0);
      acc2[ng] = __builtin_amdgcn_mfma_f32_16x16x32_bf16(a2h[t], bl, acc2[ng], 0, 0, 0);
    }
    __syncthreads();
  }
#undef STAGE

  // epilogue: out = acc2 + h + g  (also stage into LDS for fused Z-prep)
  float* OUTs = (float*)smem;  // 64 x 132 fp32 overlay (33792 B <= 51200 B)
#pragma unroll
  for (int r = 0; r < 4; ++r) {
    int rowN = n0 + wave * 16 + q * 4 + r;
    int rc = min(rowN, N - 1);
#pragma unroll
    for (int n = 0; n < 8; ++n) {
      int col = n * 16 + m16;
      float v = acc2[n][r] + h[(size_t)rc * DD + col] + g[col];
      if (DOZ) OUTs[(wave * 16 + q * 4 + r) * 132 + col] = v;
      if (rowN < N) out[(size_t)rowN * DD + col] = v;
    }
  }

  if (DOZ) {
    __syncthreads();
    // Z-GEMM for this block's 64 rows: wave w -> cols [128w, 128w+128)
#pragma unroll
    for (int half = 0; half < 2; ++half) {
      f32x4 zacc[4][4];
#pragma unroll
      for (int nt = 0; nt < 4; ++nt) {
        int col = wave * 128 + half * 64 + nt * 16 + m16;
        float b = (col < 128) ? msg_b1[col] : ((col < 256) ? att_b1[col - 128] : 0.f);
#pragma unroll
        for (int mt = 0; mt < 4; ++mt) zacc[mt][nt] = (f32x4){b, b, b, b};
      }
      for (int c = 0; c < 4; ++c) {
        short8 ah[4], al[4];
#pragma unroll
        for (int mt = 0; mt < 4; ++mt) {
          const float* p = OUTs + (mt * 16 + m16) * 132 + c * 32 + q * 8;
          float4 v0 = *(const float4*)p;
          float4 v1 = *(const float4*)(p + 4);
          float f[8] = {v0.x, v0.y, v0.z, v0.w, v1.x, v1.y, v1.z, v1.w};
#pragma unroll
          for (int j = 0; j < 8; ++j) {
            short hi, lo; splitT(f[j], hi, lo); ah[mt][j] = hi; al[mt][j] = lo;
          }
        }
#pragma unroll
        for (int nt = 0; nt < 4; ++nt) {
          int ng = wave * 8 + half * 4 + nt;
          const short* bp = WbigF + ((size_t)((c * 32 + ng) * 2) * 64 + lane) * 8;
          short8 bh = *(const short8*)bp;
          short8 bl = *(const short8*)(bp + 512);
#pragma unroll
          for (int mt = 0; mt < 4; ++mt) {
            zacc[mt][nt] = __builtin_amdgcn_mfma_f32_16x16x32_bf16(ah[mt], bh, zacc[mt][nt], 0, 0, 0);
            zacc[mt][nt] = __builtin_amdgcn_mfma_f32_16x16x32_bf16(al[mt], bh, zacc[mt][nt], 0, 0, 0);
            zacc[mt][nt] = __builtin_amdgcn_mfma_f32_16x16x32_bf16(ah[mt], bl, zacc[mt][nt], 0, 0, 0);
          }
        }
      }
#pragma unroll
      for (int mt = 0; mt < 4; ++mt)
#pragma unroll
        for (int r = 0; r < 4; ++r) {
          int row = n0 + mt * 16 + q * 4 + r;
          if (row < N) {
#pragma unroll
            for (int nt = 0; nt < 4; ++nt) {
              int col = wave * 128 + half * 64 + nt * 16 + m16;
              float v = zacc[mt][nt][r];
              if (col < 256) Zsrc[(size_t)row * 256 + col] = (_Float16)v;
              else           Zdst[(size_t)row * 256 + (col - 256)] = v;
            }
          }
        }
    }
  }
}

extern "C" void kernel_launch(void* const* d_in, const int* in_sizes, int n_in,
                              void* d_out, int out_size, void* d_ws, size_t ws_size,
                              hipStream_t stream) {
  const float* x = (const float*)d_in[0];
  const int* ei = (const int*)d_in[1];
  const float* msg_W1 = (const float*)d_in[2];
  const float* msg_b1 = (const float*)d_in[3];
  const float* msg_W2 = (const float*)d_in[4];
  const float* msg_b2 = (const float*)d_in[5];
  const float* upd_W1 = (const float*)d_in[6];
  const float* upd_b1 = (const float*)d_in[7];
  const float* upd_W2 = (const float*)d_in[8];
  const float* upd_b2 = (const float*)d_in[9];
  const float* att_W1 = (const float*)d_in[10];
  const float* att_b1 = (const float*)d_in[11];
  const float* att_W2 = (const float*)d_in[12];
  const float* att_b2 = (const float*)d_in[13];
  const float* glb_W = (const float*)d_in[14];
  const float* glb_b = (const float*)d_in[15];

  const int N = in_sizes[0] / DD;
  const int E = in_sizes[1] / 2;
  const int* src = ei;
  const int* dst = ei + E;

  float* out = (float*)d_out;
  float* aggH = (float*)d_ws;                  // N*128 f32
  float* aggA = aggH + (size_t)N * DD;         // N
  float* colsum = aggA + N;                    // 128
  float* g = colsum + DD;                      // 128
  float* W2U = g + DD;                         // 16384 f32
  float* v2 = W2U + 16384;                     // 128 f32
  short* WbigF = (short*)(v2 + DD);            // 131072 shorts
  short* U1F = WbigF + 131072;                 // 65536 shorts
  short* U2F = U1F + 65536;                    // 32768 shorts
  int* bsum = (int*)(U2F + 32768);             // 64 ints
  int* rowptr = bsum + 64;                     // N+1 ints
  int* sortedSrc = rowptr + ((N + 1 + 3) & ~3);
  _Float16* Zsrc = (_Float16*)(sortedSrc + ((E + 3) & ~3));  // N*256 fp16
  float* Zdst = (float*)(Zsrc + (size_t)N * 256);            // N*256 fp32
  int* cursor = (int*)aggH;                    // overlay during sort phase only

  wprep_kernel<<<65, 256, 0, stream>>>(msg_W2, msg_b2, upd_W1, W2U, v2);
  conv_kernel<<<112, 256, 0, stream>>>(msg_W1, att_W1, upd_W1, upd_W2, W2U,
                                       WbigF, U1F, U2F);
  zero128_kernel<<<1, 128, 0, stream>>>(colsum);
  colsum_kernel<<<256, 256, 0, stream>>>(x, colsum, N);
  glb_kernel<<<1, 128, 0, stream>>>(colsum, glb_W, glb_b, g, 1.0f / (float)N);

  // CSR build (edges identical both steps -> sort once per launch)
  hipMemsetAsync(rowptr, 0, (size_t)(N + 1) * sizeof(int), stream);
  hist_kernel<<<1024, 256, 0, stream>>>(dst, rowptr, E);
  const int nscan = N + 1;
  const int nb = (nscan + 1023) / 1024;
  scan1_kernel<<<nb, 1024, 0, stream>>>(rowptr, bsum, nscan);
  scan2_kernel<<<1, 1024, 0, stream>>>(bsum, nb);
  if (nb > 1) scan3_kernel<<<nb - 1, 1024, 0, stream>>>(rowptr, bsum, nscan);
  hipMemcpyAsync(cursor, rowptr, (size_t)N * sizeof(int), hipMemcpyDeviceToDevice, stream);
  scatter_kernel<<<1024, 256, 0, stream>>>(src, dst, cursor, sortedSrc, E);

  const int zgrid = (N + 31) / 32;
  const int agrid = (N + 7) / 8;
  const int ngrid = (N + 63) / 64;

  // step 0
  zprep_kernel<<<zgrid, 256, 0, stream>>>(x, WbigF, msg_b1, att_b1, Zsrc, Zdst, N);
  aggcsr_kernel<<<agrid, 256, 0, stream>>>(Zsrc, Zdst, rowptr, sortedSrc, att_W2, att_b2,
                                           aggH, aggA, N);
  node_mfma_kernel<1><<<ngrid, 256, 0, stream>>>(x, aggH, aggA, v2, U1F, U2F,
                                                 upd_b1, upd_b2, g, out, N,
                                                 WbigF, msg_b1, att_b1, Zsrc, Zdst);
  // step 1
  aggcsr_kernel<<<agrid, 256, 0, stream>>>(Zsrc, Zdst, rowptr, sortedSrc, att_W2, att_b2,
                                           aggH, aggA, N);
  node_mfma_kernel<0><<<ngrid, 256, 0, stream>>>(out, aggH, aggA, v2, U1F, U2F,
                                                 upd_b1, upd_b2, g, out, N,
                                                 WbigF, msg_b1, att_b1, Zsrc, Zdst);
}